// Round 3
// baseline (1755.325 us; speedup 1.0000x reference)
//
#include <hip/hip_runtime.h>
#include <hip/hip_bf16.h>
#include <math.h>

using bf16 = __hip_bfloat16;
using short8  = __attribute__((ext_vector_type(8))) short;   // 8 bf16 (4 VGPRs)
using floatx4 = __attribute__((ext_vector_type(4))) float;   // MFMA accumulator

__device__ __forceinline__ float b2f(bf16 v){ return __bfloat162float(v); }
__device__ __forceinline__ bf16  f2b(float v){ return __float2bfloat16(v); }
// dtype-adaptive load of a "reference float32" tensor that may arrive as bf16 or fp32
__device__ __forceinline__ float loadf(const void* p, size_t i, bool f32){
    return f32 ? ((const float*)p)[i] : b2f(((const bf16*)p)[i]);
}

// B=8, H=W=64, C=768, HEADS=12, WS=8, SHIFT=4, N=64, hd=64, L=4096, Mtot=32768
// ws layout: [flag 256B | mod fp32 147456 | wqkvT 3538944 | wprojT 1179648 |
//             wfc1T 4718592 | wfc2T 4718592 | chunk buffers]
#define FIXED_WS 14303488

// ---------------- runtime dtype detection ----------------
// bf16 data: essentially no "weird" bf16 words. fp32 data read as bf16: even words are
// low-mantissa garbage with uniform exponent -> ~34% weird. Threshold 200/4096.
__global__ void detect_k(const void* __restrict__ x, int* __restrict__ flag){
    __shared__ int cnt;
    if (threadIdx.x == 0) cnt = 0;
    __syncthreads();
    const unsigned short* u = (const unsigned short*)x;
    int local = 0;
    #pragma unroll
    for (int i = 0; i < 16; ++i){
        unsigned int w = u[threadIdx.x * 16 + i];
        float v = __uint_as_float(w << 16);
        float a = fabsf(v);
        if (!(a <= 1e4f) || (v != 0.f && a < 1e-20f)) local++;   // NaN fails (a<=1e4)
    }
    atomicAdd(&cnt, local);
    __syncthreads();
    if (threadIdx.x == 0) *flag = (cnt > 200) ? 1 : 0;
}

// ---------------- weight transpose (K x N -> N x K), dual-dtype source ----------------
__global__ void transpose_k(const void* __restrict__ W, bf16* __restrict__ WT, int K, int N,
                            const int* __restrict__ dflag){
    const bool f32 = (*dflag != 0);
    __shared__ bf16 t[32][33];
    int k0 = blockIdx.y * 32, n0 = blockIdx.x * 32;
    int tx = threadIdx.x, ty = threadIdx.y;           // block (32,8)
    #pragma unroll
    for (int r = ty; r < 32; r += 8) t[r][tx] = f2b(loadf(W, (size_t)(k0 + r) * N + n0 + tx, f32));
    __syncthreads();
    #pragma unroll
    for (int r = ty; r < 32; r += 8) WT[(size_t)(n0 + r) * K + k0 + tx] = t[tx][r];
}

// ---------------- adaLN modulation: mod = silu(c) @ w_adaln + b_adaln ----------------
__global__ __launch_bounds__(256) void adaln_k(const void* __restrict__ c, const void* __restrict__ w,
                                               const void* __restrict__ bv, float* __restrict__ mod,
                                               const int* __restrict__ dflag){
    const bool f32 = (*dflag != 0);
    int b = blockIdx.y;
    int j = blockIdx.x * 256 + threadIdx.x;           // [0,4608)
    __shared__ float sc[768];
    for (int k = threadIdx.x; k < 768; k += 256){
        float v = loadf(c, b * 768 + k, f32);
        sc[k] = v / (1.f + __expf(-v));
    }
    __syncthreads();
    float acc = loadf(bv, j, f32);
    for (int k = 0; k < 768; ++k) acc += sc[k] * loadf(w, (size_t)k * 4608 + j, f32);
    mod[b * 4608 + j] = acc;
}

// ---------------- block reduction helper (256 threads) ----------------
__device__ __forceinline__ float2 block_reduce_sum2(float s, float s2){
    #pragma unroll
    for (int m = 32; m >= 1; m >>= 1){
        s  += __shfl_xor(s,  m, 64);
        s2 += __shfl_xor(s2, m, 64);
    }
    __shared__ float red[8];
    int wave = threadIdx.x >> 6;
    if ((threadIdx.x & 63) == 0){ red[wave] = s; red[4 + wave] = s2; }
    __syncthreads();
    return make_float2(red[0] + red[1] + red[2] + red[3],
                       red[4] + red[5] + red[6] + red[7]);
}

// ---------------- LN + modulate + roll(-4,-4) + window partition (chunked) ----------------
__global__ __launch_bounds__(256) void ln_mod_win_k(const void* __restrict__ x, const float* __restrict__ mod,
                                                    bf16* __restrict__ win, int roff,
                                                    const int* __restrict__ dflag){
    const bool f32 = (*dflag != 0);
    int r = roff + blockIdx.x;                        // global window-layout token
    int bw = r >> 6, n = r & 63;
    int b = bw >> 6, widx = bw & 63;
    int hh = (((widx >> 3) << 3) + (n >> 3) + 4) & 63;
    int ww = (((widx & 7) << 3) + (n & 7) + 4) & 63;
    size_t xo = ((size_t)b * 4096 + hh * 64 + ww) * 768;
    int t = threadIdx.x;
    float v0 = loadf(x, xo + t, f32), v1 = loadf(x, xo + t + 256, f32), v2 = loadf(x, xo + t + 512, f32);
    float2 ss = block_reduce_sum2(v0 + v1 + v2, v0 * v0 + v1 * v1 + v2 * v2);
    float mu = ss.x * (1.f / 768.f);
    float rstd = rsqrtf(ss.y * (1.f / 768.f) - mu * mu + 1e-6f);
    const float* mb = mod + b * 4608;                 // [sh_msa | sc_msa | ...]
    bf16* wr = win + (size_t)blockIdx.x * 768;        // chunk-local
    wr[t]       = f2b((v0 - mu) * rstd * (1.f + mb[768 + t])       + mb[t]);
    wr[t + 256] = f2b((v1 - mu) * rstd * (1.f + mb[768 + t + 256]) + mb[t + 256]);
    wr[t + 512] = f2b((v2 - mu) * rstd * (1.f + mb[768 + t + 512]) + mb[t + 512]);
}

// ---------------- LN + modulate (MLP branch; x1 lives in d_out, dtype = output mode) ----------------
__global__ __launch_bounds__(256) void ln_mod2_k(const void* __restrict__ x1, const float* __restrict__ mod,
                                                 bf16* __restrict__ h2, int roff,
                                                 const int* __restrict__ dflag){
    const bool f32 = (*dflag != 0);
    int t0 = roff + blockIdx.x;                       // global image token
    int b = t0 >> 12;
    size_t xo = (size_t)t0 * 768;
    int t = threadIdx.x;
    float v0 = loadf(x1, xo + t, f32), v1 = loadf(x1, xo + t + 256, f32), v2 = loadf(x1, xo + t + 512, f32);
    float2 ss = block_reduce_sum2(v0 + v1 + v2, v0 * v0 + v1 * v1 + v2 * v2);
    float mu = ss.x * (1.f / 768.f);
    float rstd = rsqrtf(ss.y * (1.f / 768.f) - mu * mu + 1e-6f);
    const float* mb = mod + b * 4608;                 // sh_mlp @2304, sc_mlp @3072
    bf16* wr = h2 + (size_t)blockIdx.x * 768;         // chunk-local
    wr[t]       = f2b((v0 - mu) * rstd * (1.f + mb[3072 + t])       + mb[2304 + t]);
    wr[t + 256] = f2b((v1 - mu) * rstd * (1.f + mb[3072 + t + 256]) + mb[2304 + t + 256]);
    wr[t + 512] = f2b((v2 - mu) * rstd * (1.f + mb[3072 + t + 512]) + mb[2304 + t + 512]);
}

// ---------------- windowed attention: one block per (window, head), chunked ----------------
__global__ __launch_bounds__(256) void attn_k(const bf16* __restrict__ qkv, const void* __restrict__ maskm,
                                              const int* __restrict__ rel, const void* __restrict__ rpb,
                                              bf16* __restrict__ ao, int woff,
                                              const int* __restrict__ dflag){
    const bool f32 = (*dflag != 0);
    __shared__ bf16  qs[64][64];      // broadcast reads -> no pad needed
    __shared__ float ks[64][65];      // row-varying lane reads -> pad
    __shared__ bf16  vs[64][64];
    __shared__ float Ps[64][65];
    int blk = blockIdx.x;
    int head = blk % 12;
    int bw = blk / 12;                                // chunk-local window
    int tid = threadIdx.x;
    const bf16* base = qkv + (size_t)bw * 64 * 2304 + head * 64;
    for (int e = tid; e < 4096; e += 256){
        int n = e >> 6, d = e & 63;
        size_t o = (size_t)n * 2304 + d;
        qs[n][d] = f2b(b2f(base[o]) * 0.125f);        // q * hd^-0.5 (exact in bf16)
        ks[n][d] = b2f(base[o + 768]);
        vs[n][d] = base[o + 1536];
    }
    __syncthreads();
    size_t mo = (size_t)((woff + bw) & 63) * 4096;    // window idx within batch
    for (int e = tid; e < 4096; e += 256){
        int i = e >> 6, j = e & 63;
        float acc = 0.f;
        #pragma unroll
        for (int d = 0; d < 64; ++d) acc += b2f(qs[i][d]) * ks[j][d];
        acc += loadf(rpb, (size_t)rel[e] * 12 + head, f32) + loadf(maskm, mo + e, f32);
        Ps[i][j] = acc;
    }
    __syncthreads();
    if (tid < 64){
        float mx = -1e30f;
        #pragma unroll
        for (int j = 0; j < 64; ++j) mx = fmaxf(mx, Ps[tid][j]);
        float sum = 0.f;
        #pragma unroll
        for (int j = 0; j < 64; ++j){ float ev = __expf(Ps[tid][j] - mx); Ps[tid][j] = ev; sum += ev; }
        float inv = 1.f / sum;
        #pragma unroll
        for (int j = 0; j < 64; ++j) Ps[tid][j] *= inv;
    }
    __syncthreads();
    for (int e = tid; e < 4096; e += 256){
        int i = e >> 6, d = e & 63;
        float acc = 0.f;
        #pragma unroll
        for (int j = 0; j < 64; ++j) acc += Ps[i][j] * b2f(vs[j][d]);
        ao[((size_t)bw * 64 + i) * 768 + head * 64 + d] = f2b(acc);
    }
}

// ---------------- MFMA bf16 GEMM: C = A(McxK) * B(KxN) + bias, B transposed (NxK) ----------------
// EPI: 0 = store bf16 (chunk-local); 1 = exact GELU bf16 (chunk-local);
//      2 = proj epilogue: unwindow+roll+residual+gate -> x1 in d_out (output dtype);
//      3 = fc2 epilogue: out = x1 + g_mlp * v (same index read-then-write, output dtype)
template<int EPI>
__global__ __launch_bounds__(256) void gemm_k(const bf16* __restrict__ A, const bf16* __restrict__ BT,
                                              const void* __restrict__ bias, void* __restrict__ Cout,
                                              int N, int K, int roff,
                                              const void* __restrict__ xres, const float* __restrict__ mod,
                                              const void* __restrict__ x1,
                                              const int* __restrict__ dflag){
    const bool f32 = (*dflag != 0);
    __shared__ __align__(16) bf16 As[128][40];        // 80 B row stride: 16B-aligned, 2-way banks (free)
    __shared__ __align__(16) bf16 Bs[128][40];
    int m0 = blockIdx.x * 128, n0 = blockIdx.y * 128;
    int tid = threadIdx.x;
    int wave = tid >> 6, lane = tid & 63;
    int wm = (wave >> 1) * 64, wn = (wave & 1) * 64;  // 2x2 waves of 64x64
    int lrow = lane & 15, lq = lane >> 4;
    floatx4 zero4 = {0.f, 0.f, 0.f, 0.f};
    floatx4 acc[4][4];
    #pragma unroll
    for (int i = 0; i < 4; ++i)
        #pragma unroll
        for (int j = 0; j < 4; ++j) acc[i][j] = zero4;

    int srow = tid >> 2, scol = (tid & 3) * 8;        // staging: 2 vec8 per thread per tile
    for (int kt = 0; kt < K; kt += 32){
        #pragma unroll
        for (int rep = 0; rep < 2; ++rep){
            int row = rep * 64 + srow;
            *(short8*)&As[row][scol] = *(const short8*)&A [(size_t)(m0 + row) * K + kt + scol];
            *(short8*)&Bs[row][scol] = *(const short8*)&BT[(size_t)(n0 + row) * K + kt + scol];
        }
        __syncthreads();
        short8 af[4], bfr[4];
        #pragma unroll
        for (int f = 0; f < 4; ++f){
            af[f]  = *(const short8*)&As[wm + f * 16 + lrow][lq * 8];
            bfr[f] = *(const short8*)&Bs[wn + f * 16 + lrow][lq * 8];
        }
        #pragma unroll
        for (int mf = 0; mf < 4; ++mf)
            #pragma unroll
            for (int nf = 0; nf < 4; ++nf)
                acc[mf][nf] = __builtin_amdgcn_mfma_f32_16x16x32_bf16(af[mf], bfr[nf], acc[mf][nf], 0, 0, 0);
        __syncthreads();
    }
    // epilogue: D row = lq*4+r, col = lrow  (verified m89 mapping)
    #pragma unroll
    for (int mf = 0; mf < 4; ++mf){
        #pragma unroll
        for (int nf = 0; nf < 4; ++nf){
            #pragma unroll
            for (int r = 0; r < 4; ++r){
                int grow = m0 + wm + mf * 16 + lq * 4 + r;   // chunk-local row
                int gcol = n0 + wn + nf * 16 + lrow;
                float v = acc[mf][nf][r] + loadf(bias, gcol, f32);
                if (EPI == 0){
                    ((bf16*)Cout)[(size_t)grow * N + gcol] = f2b(v);
                } else if (EPI == 1){
                    float g = 0.5f * v * (1.f + erff(v * 0.70710678118654752f));
                    ((bf16*)Cout)[(size_t)grow * N + gcol] = f2b(g);
                } else if (EPI == 2){
                    int gr = roff + grow;                    // global window-layout row
                    int bw = gr >> 6, n = gr & 63;
                    int b = bw >> 6, widx = bw & 63;
                    int hh = (((widx >> 3) << 3) + (n >> 3) + 4) & 63;
                    int ww = (((widx & 7) << 3) + (n & 7) + 4) & 63;
                    size_t t = ((size_t)b * 4096 + hh * 64 + ww) * 768 + gcol;
                    float g = mod[b * 4608 + 1536 + gcol];   // g_msa
                    float res = loadf(xres, t, f32) + g * v;
                    if (f32) ((float*)Cout)[t] = res; else ((bf16*)Cout)[t] = f2b(res);
                } else {
                    int gr = roff + grow;                    // global image row
                    int b = gr >> 12;
                    float g = mod[b * 4608 + 3840 + gcol];   // g_mlp
                    size_t t = (size_t)gr * N + gcol;
                    float res = loadf(x1, t, f32) + g * v;   // read x1 then overwrite same idx
                    if (f32) ((float*)Cout)[t] = res; else ((bf16*)Cout)[t] = f2b(res);
                }
            }
        }
    }
}

extern "C" void kernel_launch(void* const* d_in, const int* in_sizes, int n_in,
                              void* d_out, int out_size, void* d_ws, size_t ws_size,
                              hipStream_t stream){
    const void* x       = d_in[0];
    const void* c       = d_in[1];
    const void* maskm   = d_in[2];
    const int*  rel     = (const int*)d_in[3];
    const void* w_adaln = d_in[4];
    const void* b_adaln = d_in[5];
    const void* w_qkv   = d_in[6];
    const void* b_qkv   = d_in[7];
    const void* rpb     = d_in[8];
    const void* w_proj  = d_in[9];
    const void* b_proj  = d_in[10];
    const void* w_fc1   = d_in[11];
    const void* b_fc1   = d_in[12];
    const void* w_fc2   = d_in[13];
    const void* b_fc2   = d_in[14];

    // pick chunk count so the workspace fits (ws_size constant across calls -> graph-safe)
    int nc = 256;
    for (int cand = 4; cand <= 256; cand *= 2){
        size_t mc = 32768u / cand;
        if (FIXED_WS + mc * 9216u <= ws_size){ nc = cand; break; }
    }
    const int Mc = 32768 / nc;                        // rows per chunk (multiple of 128)

    char* ws = (char*)d_ws;
    int*  dflag  = (int*)(ws);
    float* mod   = (float*)(ws + 256);
    bf16* wqkvT  = (bf16*)(ws + 147712);
    bf16* wprojT = (bf16*)(ws + 3686656);
    bf16* wfc1T  = (bf16*)(ws + 4866304);
    bf16* wfc2T  = (bf16*)(ws + 9584896);
    bf16* win_c  = (bf16*)(ws + FIXED_WS);                         // Mc*768 bf16 (reused as h2_c)
    bf16* big_c  = (bf16*)(ws + FIXED_WS + (size_t)Mc * 1536);     // Mc*3072 bf16 (qkv_c / fc1o_c)
    bf16* ao_c   = (bf16*)(ws + FIXED_WS + (size_t)Mc * 7680);     // Mc*768 bf16
    void* x1     = d_out;                                          // aliased into d_out (output dtype)
    void* out    = d_out;

    detect_k<<<1, 256, 0, stream>>>(x, dflag);

    dim3 tb(32, 8);
    transpose_k<<<dim3(2304/32, 768/32),  tb, 0, stream>>>(w_qkv,  wqkvT,  768, 2304, dflag);
    transpose_k<<<dim3(768/32,  768/32),  tb, 0, stream>>>(w_proj, wprojT, 768, 768, dflag);
    transpose_k<<<dim3(3072/32, 768/32),  tb, 0, stream>>>(w_fc1,  wfc1T,  768, 3072, dflag);
    transpose_k<<<dim3(768/32,  3072/32), tb, 0, stream>>>(w_fc2,  wfc2T,  3072, 768, dflag);
    adaln_k<<<dim3(18, 8), 256, 0, stream>>>(c, w_adaln, b_adaln, mod, dflag);

    // ---- MSA phase, chunked over windows ----
    for (int ch = 0; ch < nc; ++ch){
        int roff = ch * Mc;
        ln_mod_win_k<<<Mc, 256, 0, stream>>>(x, mod, win_c, roff, dflag);
        gemm_k<0><<<dim3(Mc/128, 18), 256, 0, stream>>>(win_c, wqkvT, b_qkv, big_c,
                                                        2304, 768, 0, nullptr, nullptr, nullptr, dflag);
        attn_k<<<(Mc/64) * 12, 256, 0, stream>>>(big_c, maskm, rel, rpb, ao_c, roff / 64, dflag);
        gemm_k<2><<<dim3(Mc/128, 6), 256, 0, stream>>>(ao_c, wprojT, b_proj, x1,
                                                       768, 768, roff, x, mod, nullptr, dflag);
    }
    // ---- MLP phase, chunked over tokens ----
    for (int ch = 0; ch < nc; ++ch){
        int roff = ch * Mc;
        ln_mod2_k<<<Mc, 256, 0, stream>>>(x1, mod, win_c, roff, dflag);
        gemm_k<1><<<dim3(Mc/128, 24), 256, 0, stream>>>(win_c, wfc1T, b_fc1, big_c,
                                                        3072, 768, 0, nullptr, nullptr, nullptr, dflag);
        gemm_k<3><<<dim3(Mc/128, 6), 256, 0, stream>>>(big_c, wfc2T, b_fc2, out,
                                                       768, 3072, roff, nullptr, mod, x1, dflag);
    }
}

// Round 4
// 1704.078 us; speedup vs baseline: 1.0301x; 1.0301x over previous
//
#include <hip/hip_runtime.h>
#include <hip/hip_bf16.h>
#include <math.h>

using bf16 = __hip_bfloat16;
using short8  = __attribute__((ext_vector_type(8))) short;   // 8 bf16 (4 VGPRs)
using floatx4 = __attribute__((ext_vector_type(4))) float;   // MFMA accumulator

__device__ __forceinline__ float b2f(bf16 v){ return __bfloat162float(v); }
__device__ __forceinline__ bf16  f2b(float v){ return __float2bfloat16(v); }
// dtype-adaptive load of a "reference float32" tensor that may arrive as bf16 or fp32
__device__ __forceinline__ float loadf(const void* p, size_t i, bool f32){
    return f32 ? ((const float*)p)[i] : b2f(((const bf16*)p)[i]);
}
// async global->LDS DMA, 16 B per lane; lds dest = wave-uniform base + lane*16
__device__ __forceinline__ void gload16(const void* g, void* l){
    __builtin_amdgcn_global_load_lds(
        (const __attribute__((address_space(1))) unsigned int*)g,
        (__attribute__((address_space(3))) unsigned int*)l, 16, 0, 0);
}

// B=8, H=W=64, C=768, HEADS=12, WS=8, SHIFT=4, N=64, hd=64, L=4096, Mtot=32768
// ws layout: [flag 256B | mod fp32 147456 | wqkvT 3538944 | wprojT 1179648 |
//             wfc1T 4718592 | wfc2T 4718592 | chunk buffers]
#define FIXED_WS 14303488

// ---------------- runtime dtype detection ----------------
__global__ void detect_k(const void* __restrict__ x, int* __restrict__ flag){
    __shared__ int cnt;
    if (threadIdx.x == 0) cnt = 0;
    __syncthreads();
    const unsigned short* u = (const unsigned short*)x;
    int local = 0;
    #pragma unroll
    for (int i = 0; i < 16; ++i){
        unsigned int w = u[threadIdx.x * 16 + i];
        float v = __uint_as_float(w << 16);
        float a = fabsf(v);
        if (!(a <= 1e4f) || (v != 0.f && a < 1e-20f)) local++;   // NaN fails (a<=1e4)
    }
    atomicAdd(&cnt, local);
    __syncthreads();
    if (threadIdx.x == 0) *flag = (cnt > 200) ? 1 : 0;
}

// ---------------- weight transpose (K x N -> N x K), dual-dtype source ----------------
__global__ void transpose_k(const void* __restrict__ W, bf16* __restrict__ WT, int K, int N,
                            const int* __restrict__ dflag){
    const bool f32 = (*dflag != 0);
    __shared__ bf16 t[32][33];
    int k0 = blockIdx.y * 32, n0 = blockIdx.x * 32;
    int tx = threadIdx.x, ty = threadIdx.y;           // block (32,8)
    #pragma unroll
    for (int r = ty; r < 32; r += 8) t[r][tx] = f2b(loadf(W, (size_t)(k0 + r) * N + n0 + tx, f32));
    __syncthreads();
    #pragma unroll
    for (int r = ty; r < 32; r += 8) WT[(size_t)(n0 + r) * K + k0 + tx] = t[tx][r];
}

// ---------------- adaLN modulation: mod = silu(c) @ w_adaln + b_adaln ----------------
__global__ __launch_bounds__(256) void adaln_k(const void* __restrict__ c, const void* __restrict__ w,
                                               const void* __restrict__ bv, float* __restrict__ mod,
                                               const int* __restrict__ dflag){
    const bool f32 = (*dflag != 0);
    int b = blockIdx.y;
    int j = blockIdx.x * 256 + threadIdx.x;           // [0,4608)
    __shared__ float sc[768];
    for (int k = threadIdx.x; k < 768; k += 256){
        float v = loadf(c, b * 768 + k, f32);
        sc[k] = v / (1.f + __expf(-v));
    }
    __syncthreads();
    float acc = loadf(bv, j, f32);
    for (int k = 0; k < 768; ++k) acc += sc[k] * loadf(w, (size_t)k * 4608 + j, f32);
    mod[b * 4608 + j] = acc;
}

// ---------------- block reduction helper (256 threads) ----------------
__device__ __forceinline__ float2 block_reduce_sum2(float s, float s2){
    #pragma unroll
    for (int m = 32; m >= 1; m >>= 1){
        s  += __shfl_xor(s,  m, 64);
        s2 += __shfl_xor(s2, m, 64);
    }
    __shared__ float red[8];
    int wave = threadIdx.x >> 6;
    if ((threadIdx.x & 63) == 0){ red[wave] = s; red[4 + wave] = s2; }
    __syncthreads();
    return make_float2(red[0] + red[1] + red[2] + red[3],
                       red[4] + red[5] + red[6] + red[7]);
}

// ---------------- LN + modulate + roll(-4,-4) + window partition (chunked) ----------------
__global__ __launch_bounds__(256) void ln_mod_win_k(const void* __restrict__ x, const float* __restrict__ mod,
                                                    bf16* __restrict__ win, int roff,
                                                    const int* __restrict__ dflag){
    const bool f32 = (*dflag != 0);
    int r = roff + blockIdx.x;                        // global window-layout token
    int bw = r >> 6, n = r & 63;
    int b = bw >> 6, widx = bw & 63;
    int hh = (((widx >> 3) << 3) + (n >> 3) + 4) & 63;
    int ww = (((widx & 7) << 3) + (n & 7) + 4) & 63;
    size_t xo = ((size_t)b * 4096 + hh * 64 + ww) * 768;
    int t = threadIdx.x;
    float v0 = loadf(x, xo + t, f32), v1 = loadf(x, xo + t + 256, f32), v2 = loadf(x, xo + t + 512, f32);
    float2 ss = block_reduce_sum2(v0 + v1 + v2, v0 * v0 + v1 * v1 + v2 * v2);
    float mu = ss.x * (1.f / 768.f);
    float rstd = rsqrtf(ss.y * (1.f / 768.f) - mu * mu + 1e-6f);
    const float* mb = mod + b * 4608;                 // [sh_msa | sc_msa | ...]
    bf16* wr = win + (size_t)blockIdx.x * 768;        // chunk-local
    wr[t]       = f2b((v0 - mu) * rstd * (1.f + mb[768 + t])       + mb[t]);
    wr[t + 256] = f2b((v1 - mu) * rstd * (1.f + mb[768 + t + 256]) + mb[t + 256]);
    wr[t + 512] = f2b((v2 - mu) * rstd * (1.f + mb[768 + t + 512]) + mb[t + 512]);
}

// ---------------- LN + modulate (MLP branch; x1 lives in d_out, dtype = output mode) ----------------
__global__ __launch_bounds__(256) void ln_mod2_k(const void* __restrict__ x1, const float* __restrict__ mod,
                                                 bf16* __restrict__ h2, int roff,
                                                 const int* __restrict__ dflag){
    const bool f32 = (*dflag != 0);
    int t0 = roff + blockIdx.x;                       // global image token
    int b = t0 >> 12;
    size_t xo = (size_t)t0 * 768;
    int t = threadIdx.x;
    float v0 = loadf(x1, xo + t, f32), v1 = loadf(x1, xo + t + 256, f32), v2 = loadf(x1, xo + t + 512, f32);
    float2 ss = block_reduce_sum2(v0 + v1 + v2, v0 * v0 + v1 * v1 + v2 * v2);
    float mu = ss.x * (1.f / 768.f);
    float rstd = rsqrtf(ss.y * (1.f / 768.f) - mu * mu + 1e-6f);
    const float* mb = mod + b * 4608;                 // sh_mlp @2304, sc_mlp @3072
    bf16* wr = h2 + (size_t)blockIdx.x * 768;         // chunk-local
    wr[t]       = f2b((v0 - mu) * rstd * (1.f + mb[3072 + t])       + mb[2304 + t]);
    wr[t + 256] = f2b((v1 - mu) * rstd * (1.f + mb[3072 + t + 256]) + mb[2304 + t + 256]);
    wr[t + 512] = f2b((v2 - mu) * rstd * (1.f + mb[3072 + t + 512]) + mb[2304 + t + 512]);
}

// ---------------- windowed attention: one block per (window, head), chunked ----------------
__global__ __launch_bounds__(256) void attn_k(const bf16* __restrict__ qkv, const void* __restrict__ maskm,
                                              const int* __restrict__ rel, const void* __restrict__ rpb,
                                              bf16* __restrict__ ao, int woff,
                                              const int* __restrict__ dflag){
    const bool f32 = (*dflag != 0);
    __shared__ bf16  qs[64][64];      // broadcast reads -> no pad needed
    __shared__ float ks[64][65];      // row-varying lane reads -> pad
    __shared__ bf16  vs[64][64];
    __shared__ float Ps[64][65];
    int blk = blockIdx.x;
    int head = blk % 12;
    int bw = blk / 12;                                // chunk-local window
    int tid = threadIdx.x;
    const bf16* base = qkv + (size_t)bw * 64 * 2304 + head * 64;
    for (int e = tid; e < 4096; e += 256){
        int n = e >> 6, d = e & 63;
        size_t o = (size_t)n * 2304 + d;
        qs[n][d] = f2b(b2f(base[o]) * 0.125f);        // q * hd^-0.5 (exact in bf16)
        ks[n][d] = b2f(base[o + 768]);
        vs[n][d] = base[o + 1536];
    }
    __syncthreads();
    size_t mo = (size_t)((woff + bw) & 63) * 4096;    // window idx within batch
    for (int e = tid; e < 4096; e += 256){
        int i = e >> 6, j = e & 63;
        float acc = 0.f;
        #pragma unroll
        for (int d = 0; d < 64; ++d) acc += b2f(qs[i][d]) * ks[j][d];
        acc += loadf(rpb, (size_t)rel[e] * 12 + head, f32) + loadf(maskm, mo + e, f32);
        Ps[i][j] = acc;
    }
    __syncthreads();
    if (tid < 64){
        float mx = -1e30f;
        #pragma unroll
        for (int j = 0; j < 64; ++j) mx = fmaxf(mx, Ps[tid][j]);
        float sum = 0.f;
        #pragma unroll
        for (int j = 0; j < 64; ++j){ float ev = __expf(Ps[tid][j] - mx); Ps[tid][j] = ev; sum += ev; }
        float inv = 1.f / sum;
        #pragma unroll
        for (int j = 0; j < 64; ++j) Ps[tid][j] *= inv;
    }
    __syncthreads();
    for (int e = tid; e < 4096; e += 256){
        int i = e >> 6, d = e & 63;
        float acc = 0.f;
        #pragma unroll
        for (int j = 0; j < 64; ++j) acc += Ps[i][j] * b2f(vs[j][d]);
        ao[((size_t)bw * 64 + i) * 768 + head * 64 + d] = f2b(acc);
    }
}

// ---------------- MFMA bf16 GEMM, m97-style global_load_lds staging ----------------
// LDS layout: [128 rows][32 cols] contiguous (64 B/row), with the 16-B chunk of data-index c
// for row r stored at slot (c + (r>>1)) & 3 -> fragment ds_read_b128 is 2-way (free).
// EPI: 0 = store bf16 (chunk-local); 1 = exact GELU bf16 (chunk-local);
//      2 = proj epilogue: unwindow+roll+residual+gate -> x1 in d_out (output dtype);
//      3 = fc2 epilogue: out = x1 + g_mlp * v (same index read-then-write, output dtype)
template<int EPI>
__global__ __launch_bounds__(256) void gemm_k(const bf16* __restrict__ A, const bf16* __restrict__ BT,
                                              const void* __restrict__ bias, void* __restrict__ Cout,
                                              int N, int K, int roff,
                                              const void* __restrict__ xres, const float* __restrict__ mod,
                                              const void* __restrict__ x1,
                                              const int* __restrict__ dflag){
    const bool f32 = (*dflag != 0);
    __shared__ __align__(16) bf16 As[128 * 32];
    __shared__ __align__(16) bf16 Bs[128 * 32];
    int m0 = blockIdx.x * 128, n0 = blockIdx.y * 128;
    int tid = threadIdx.x;
    int wave = tid >> 6, lane = tid & 63;
    int wm = (wave >> 1) * 64, wn = (wave & 1) * 64;  // 2x2 waves of 64x64
    int lrow = lane & 15, lq = lane >> 4;
    floatx4 zero4 = {0.f, 0.f, 0.f, 0.f};
    floatx4 acc[4][4];
    #pragma unroll
    for (int i = 0; i < 4; ++i)
        #pragma unroll
        for (int j = 0; j < 4; ++j) acc[i][j] = zero4;

    // staging: wave w, instr i covers rows w*32+i*16 .. +16 (16 rows x 64 B = 1 KB).
    // lane's LDS slot = row w*32+i*16+(lane>>2), chunk lane&3; it must carry data chunk
    // c = ((lane&3) - ((lane>>3)&3)) & 3 (inverse of the (r>>1) rotation; wave base rows
    // are multiples of 16 so only (lane>>2)>>1 = lane>>3 matters).
    int sc8 = ((((lane & 3) - ((lane >> 3) & 3)) & 3)) * 8;  // source chunk elem offset
    int srw = lane >> 2;                                      // 0..15 within 16-row group
    const bf16* ga0 = A  + (size_t)(m0 + wave * 32 + srw) * K + sc8;
    const bf16* ga1 = ga0 + (size_t)16 * K;
    const bf16* gb0 = BT + (size_t)(n0 + wave * 32 + srw) * K + sc8;
    const bf16* gb1 = gb0 + (size_t)16 * K;
    bf16* la0 = As + (wave * 32) * 32;                        // wave-uniform LDS bases
    bf16* la1 = As + (wave * 32 + 16) * 32;
    bf16* lb0 = Bs + (wave * 32) * 32;
    bf16* lb1 = Bs + (wave * 32 + 16) * 32;

    // fragment read offsets (elements), with inverse swizzle; (row>>1)&3 == (lrow>>1)&3
    int fsw = ((lq + ((lrow >> 1) & 3)) & 3) * 8;
    int aoff = (wm + lrow) * 32 + fsw;
    int boff = (wn + lrow) * 32 + fsw;

    for (int kt = 0; kt < K; kt += 32){
        gload16(ga0, la0); gload16(ga1, la1);
        gload16(gb0, lb0); gload16(gb1, lb1);
        ga0 += 32; ga1 += 32; gb0 += 32; gb1 += 32;
        __syncthreads();                                      // drains vmcnt -> LDS valid
        short8 af[4], bfr[4];
        #pragma unroll
        for (int f = 0; f < 4; ++f){
            af[f]  = *(const short8*)(As + aoff + f * 16 * 32);
            bfr[f] = *(const short8*)(Bs + boff + f * 16 * 32);
        }
        #pragma unroll
        for (int mf = 0; mf < 4; ++mf)
            #pragma unroll
            for (int nf = 0; nf < 4; ++nf)
                acc[mf][nf] = __builtin_amdgcn_mfma_f32_16x16x32_bf16(af[mf], bfr[nf], acc[mf][nf], 0, 0, 0);
        __syncthreads();
    }
    // epilogue: D row = lq*4+r, col = lrow  (verified m89 mapping)
    #pragma unroll
    for (int mf = 0; mf < 4; ++mf){
        #pragma unroll
        for (int nf = 0; nf < 4; ++nf){
            #pragma unroll
            for (int r = 0; r < 4; ++r){
                int grow = m0 + wm + mf * 16 + lq * 4 + r;   // chunk-local row
                int gcol = n0 + wn + nf * 16 + lrow;
                float v = acc[mf][nf][r] + loadf(bias, gcol, f32);
                if (EPI == 0){
                    ((bf16*)Cout)[(size_t)grow * N + gcol] = f2b(v);
                } else if (EPI == 1){
                    float g = 0.5f * v * (1.f + erff(v * 0.70710678118654752f));
                    ((bf16*)Cout)[(size_t)grow * N + gcol] = f2b(g);
                } else if (EPI == 2){
                    int gr = roff + grow;                    // global window-layout row
                    int bw = gr >> 6, n = gr & 63;
                    int b = bw >> 6, widx = bw & 63;
                    int hh = (((widx >> 3) << 3) + (n >> 3) + 4) & 63;
                    int ww = (((widx & 7) << 3) + (n & 7) + 4) & 63;
                    size_t t = ((size_t)b * 4096 + hh * 64 + ww) * 768 + gcol;
                    float g = mod[b * 4608 + 1536 + gcol];   // g_msa
                    float res = loadf(xres, t, f32) + g * v;
                    if (f32) ((float*)Cout)[t] = res; else ((bf16*)Cout)[t] = f2b(res);
                } else {
                    int gr = roff + grow;                    // global image row
                    int b = gr >> 12;
                    float g = mod[b * 4608 + 3840 + gcol];   // g_mlp
                    size_t t = (size_t)gr * N + gcol;
                    float res = loadf(x1, t, f32) + g * v;   // read x1 then overwrite same idx
                    if (f32) ((float*)Cout)[t] = res; else ((bf16*)Cout)[t] = f2b(res);
                }
            }
        }
    }
}

extern "C" void kernel_launch(void* const* d_in, const int* in_sizes, int n_in,
                              void* d_out, int out_size, void* d_ws, size_t ws_size,
                              hipStream_t stream){
    const void* x       = d_in[0];
    const void* c       = d_in[1];
    const void* maskm   = d_in[2];
    const int*  rel     = (const int*)d_in[3];
    const void* w_adaln = d_in[4];
    const void* b_adaln = d_in[5];
    const void* w_qkv   = d_in[6];
    const void* b_qkv   = d_in[7];
    const void* rpb     = d_in[8];
    const void* w_proj  = d_in[9];
    const void* b_proj  = d_in[10];
    const void* w_fc1   = d_in[11];
    const void* b_fc1   = d_in[12];
    const void* w_fc2   = d_in[13];
    const void* b_fc2   = d_in[14];

    // pick chunk count so the workspace fits (ws_size constant across calls -> graph-safe)
    int nc = 256;
    for (int cand = 4; cand <= 256; cand *= 2){
        size_t mc = 32768u / cand;
        if (FIXED_WS + mc * 9216u <= ws_size){ nc = cand; break; }
    }
    const int Mc = 32768 / nc;                        // rows per chunk (multiple of 128)

    char* ws = (char*)d_ws;
    int*  dflag  = (int*)(ws);
    float* mod   = (float*)(ws + 256);
    bf16* wqkvT  = (bf16*)(ws + 147712);
    bf16* wprojT = (bf16*)(ws + 3686656);
    bf16* wfc1T  = (bf16*)(ws + 4866304);
    bf16* wfc2T  = (bf16*)(ws + 9584896);
    bf16* win_c  = (bf16*)(ws + FIXED_WS);                         // Mc*768 bf16 (reused as h2_c)
    bf16* big_c  = (bf16*)(ws + FIXED_WS + (size_t)Mc * 1536);     // Mc*3072 bf16 (qkv_c / fc1o_c)
    bf16* ao_c   = (bf16*)(ws + FIXED_WS + (size_t)Mc * 7680);     // Mc*768 bf16
    void* x1     = d_out;                                          // aliased into d_out (output dtype)
    void* out    = d_out;

    detect_k<<<1, 256, 0, stream>>>(x, dflag);

    dim3 tb(32, 8);
    transpose_k<<<dim3(2304/32, 768/32),  tb, 0, stream>>>(w_qkv,  wqkvT,  768, 2304, dflag);
    transpose_k<<<dim3(768/32,  768/32),  tb, 0, stream>>>(w_proj, wprojT, 768, 768, dflag);
    transpose_k<<<dim3(3072/32, 768/32),  tb, 0, stream>>>(w_fc1,  wfc1T,  768, 3072, dflag);
    transpose_k<<<dim3(768/32,  3072/32), tb, 0, stream>>>(w_fc2,  wfc2T,  3072, 768, dflag);
    adaln_k<<<dim3(18, 8), 256, 0, stream>>>(c, w_adaln, b_adaln, mod, dflag);

    // ---- MSA phase, chunked over windows ----
    for (int ch = 0; ch < nc; ++ch){
        int roff = ch * Mc;
        ln_mod_win_k<<<Mc, 256, 0, stream>>>(x, mod, win_c, roff, dflag);
        gemm_k<0><<<dim3(Mc/128, 18), 256, 0, stream>>>(win_c, wqkvT, b_qkv, big_c,
                                                        2304, 768, 0, nullptr, nullptr, nullptr, dflag);
        attn_k<<<(Mc/64) * 12, 256, 0, stream>>>(big_c, maskm, rel, rpb, ao_c, roff / 64, dflag);
        gemm_k<2><<<dim3(Mc/128, 6), 256, 0, stream>>>(ao_c, wprojT, b_proj, x1,
                                                       768, 768, roff, x, mod, nullptr, dflag);
    }
    // ---- MLP phase, chunked over tokens ----
    for (int ch = 0; ch < nc; ++ch){
        int roff = ch * Mc;
        ln_mod2_k<<<Mc, 256, 0, stream>>>(x1, mod, win_c, roff, dflag);
        gemm_k<1><<<dim3(Mc/128, 24), 256, 0, stream>>>(win_c, wfc1T, b_fc1, big_c,
                                                        3072, 768, 0, nullptr, nullptr, nullptr, dflag);
        gemm_k<3><<<dim3(Mc/128, 6), 256, 0, stream>>>(big_c, wfc2T, b_fc2, out,
                                                       768, 3072, roff, nullptr, mod, x1, dflag);
    }
}